// Round 11
// baseline (313.509 us; speedup 1.0000x reference)
//
#include <hip/hip_runtime.h>

#define NN 8192
#define HH 64
constexpr float LALPHA = 0.2f;

typedef __attribute__((ext_vector_type(8))) short bf16x8;
typedef __attribute__((ext_vector_type(4))) float f32x4;

__device__ inline short f2bf(float f) {
  unsigned u = __builtin_bit_cast(unsigned, f);
  u += 0x7FFFu + ((u >> 16) & 1u);
  return (short)(u >> 16);
}

// ---------------------------------------------------------------- prep: ht transpose + diag + col-sum partials + zero counts
__global__ __launch_bounds__(256) void k_prep(const float* __restrict__ h,
                                              const float* __restrict__ na,
                                              const float* __restrict__ ea,
                                              unsigned short* __restrict__ ht,
                                              float* __restrict__ dn,
                                              float* __restrict__ de,
                                              float* __restrict__ HbP,
                                              int* __restrict__ cpI) {
  __shared__ float tile[64][65];
  const int j0 = blockIdx.x * 64;
  for (int l = threadIdx.x; l < 64 * 64; l += 256) {
    int r = l >> 6, c = l & 63;
    tile[r][c] = h[(size_t)(j0 + r) * HH + c];
  }
  __syncthreads();
  for (int l = threadIdx.x; l < 64 * 64; l += 256) {
    int c = l >> 6, r = l & 63;
    ht[(size_t)c * NN + j0 + r] = (unsigned short)f2bf(tile[r][c]);
  }
  const int t = threadIdx.x;
  if (t < 64) {
    float s = 0.f;
    for (int r = 0; r < 64; ++r) s += tile[r][t];
    HbP[blockIdx.x * 64 + t] = s;
    cpI[j0 + t] = 0;
  } else if (t < 128) {
    int i = j0 + (t - 64);
    dn[i] = na[(size_t)i * NN + i];
    de[i] = ea[(size_t)i * NN + i];
    cpI[j0 + (t - 64) + 0] = 0;  // redundant-safe; ensure full zeroing below
  }
  if (t < 64) { /* already zeroed 64 */ }
  else if (t >= 192) { cpI[j0 + (t - 192)] = 0; }  // no-op duplicate safety
}

// ---------------------------------------------------------------- adjacency compression stream (m13-pattern)
// blocks [0,half): na -> 1-bit mask.  blocks [half,2*half): ea -> bf16 + row counts.
__global__ __launch_bounds__(256) void k_prep2(const float* __restrict__ na,
                                               const float* __restrict__ ea,
                                               unsigned char* __restrict__ mask,
                                               unsigned short* __restrict__ ebf,
                                               int* __restrict__ cpI) {
  const long long NG = (long long)NN * NN / 8;  // 8-float groups
  const int half = gridDim.x >> 1;
  const bool isNA = (int)blockIdx.x < half;
  const long long b0 = (long long)(isNA ? blockIdx.x : blockIdx.x - half);
  const long long stride = (long long)half * 256;
  for (long long g = b0 * 256 + threadIdx.x; g < NG; g += stride) {
    if (isNA) {
      const f32x4 v0 = *reinterpret_cast<const f32x4*>(na + g * 8);
      const f32x4 v1 = *reinterpret_cast<const f32x4*>(na + g * 8 + 4);
      unsigned m = 0;
#pragma unroll
      for (int q = 0; q < 4; ++q) {
        m |= (v0[q] > 0.f) ? (1u << q) : 0u;
        m |= (v1[q] > 0.f) ? (1u << (q + 4)) : 0u;
      }
      mask[g] = (unsigned char)m;
    } else {
      const f32x4 v0 = *reinterpret_cast<const f32x4*>(ea + g * 8);
      const f32x4 v1 = *reinterpret_cast<const f32x4*>(ea + g * 8 + 4);
      bf16x8 o;
      int tot = 0;
#pragma unroll
      for (int q = 0; q < 4; ++q) {
        o[q] = f2bf(v0[q]);
        o[q + 4] = f2bf(v1[q]);
        tot += (v0[q] > 0.f) ? 1 : 0;
        tot += (v1[q] > 0.f) ? 1 : 0;
      }
      *reinterpret_cast<bf16x8*>(ebf + g * 8) = o;
#pragma unroll
      for (int off = 32; off >= 1; off >>= 1) tot += __shfl_xor(tot, off);
      if ((threadIdx.x & 63) == 0) atomicAdd(&cpI[(int)(g >> 10)], tot);
    }
  }
}

// ---------------------------------------------------------------- weight prep (unchanged)
__global__ __launch_bounds__(256) void k_wprep(
    const float* __restrict__ W, const float* __restrict__ ag,
    const float* __restrict__ wihe, const float* __restrict__ whhe,
    const float* __restrict__ wihn, const float* __restrict__ whhn,
    const float* __restrict__ HbP, float* __restrict__ Hb,
    float* __restrict__ wa0, float* __restrict__ wa1,
    float* __restrict__ wihTe, float* __restrict__ whhTe,
    float* __restrict__ WnT, float* __restrict__ whhTn) {
  const int bid = blockIdx.x, t = threadIdx.x;
  if (bid == 64) {
    __shared__ float sW[64][64];
    __shared__ float sa[128];
    for (int l = t; l < 4096; l += 256) sW[l >> 6][l & 63] = W[l];
    if (t < 128) sa[t] = ag[t];
    __syncthreads();
    if (t < 64) {
      float s0 = 0.f, s1 = 0.f;
      for (int j = 0; j < 64; ++j) {
        s0 += sW[t][j] * sa[j];
        s1 += sW[t][j] * sa[64 + j];
      }
      wa0[t] = s0;
      wa1[t] = s1;
    } else if (t < 128) {
      int c = t - 64;
      float s = 0.f;
      for (int b = 0; b < 128; ++b) s += HbP[b * 64 + c];
      Hb[c] = s;
    }
    return;
  }
  for (int x = bid * 256 + t; x < 49152; x += 64 * 256) {
    if (x < 24576) {
      int k = x / 192, g = x % 192;
      wihTe[x] = wihe[g * 128 + k];
    } else if (x < 36864) {
      int o = x - 24576, k = o / 192, g = o % 192;
      whhTe[o] = whhe[g * 64 + k];
    } else {
      int o = x - 36864, k = o / 192, g = o % 192;
      whhTn[o] = whhn[g * 64 + k];
    }
  }
  if (bid < 48) {
    const int o = bid * 256 + t;
    const int k = o / 192, g = o % 192;
    float s = 0.f;
    for (int j = 0; j < 64; ++j) s += wihn[g * 64 + j] * W[k * 64 + j];
    WnT[o] = s;
  }
}

// ---------------------------------------------------------------- compressed MFMA stage: mask(1b) + ea(bf16), staggered
template <int KS>
__global__ __launch_bounds__(256, 4) void k_stageB(
    const unsigned char* __restrict__ mask, const unsigned short* __restrict__ ebf,
    const unsigned short* __restrict__ ht,
    float* __restrict__ SpP, float* __restrict__ TfP, float* __restrict__ TpP) {
  const int lane  = threadIdx.x & 63;
  const int wid   = threadIdx.x >> 6;
  const int row16 = lane & 15;
  const int kgrp  = lane >> 4;
  const int i0    = blockIdx.x * 64 + wid * 16;
  const int ks    = blockIdx.y;
  const int kbeg  = ks * (NN / KS);
  constexpr int ITERS = NN / KS / 32;
  const int start = blockIdx.x & (ITERS - 1);

  f32x4 accS[4] = {}, accF[4] = {}, accP[4] = {};

  const unsigned char* mRow = mask + (size_t)(i0 + row16) * (NN / 8) + (kbeg >> 3) + kgrp;
  const unsigned short* eRow = ebf + (size_t)(i0 + row16) * NN + kbeg + kgrp * 8;

  for (int it = 0; it < ITERS; ++it) {
    int tt = start + it;
    if (tt >= ITERS) tt -= ITERS;
    const unsigned mb = mRow[tt * 4];
    const bf16x8 fF = *reinterpret_cast<const bf16x8*>(eRow + tt * 32);
    bf16x8 fS, fP;
#pragma unroll
    for (int q = 0; q < 8; ++q) {
      fS[q] = ((mb >> q) & 1u) ? (short)0x3F80 : (short)0;
      const short sv = fF[q];
      fP[q] = (sv > 0) ? sv : (short)0;  // bf16 sign test on raw bits
    }
    const int kk = kbeg + tt * 32 + kgrp * 8;
#pragma unroll
    for (int c = 0; c < 4; ++c) {
      const bf16x8 fB = *reinterpret_cast<const bf16x8*>(
          ht + (size_t)(c * 16 + row16) * NN + kk);
      accS[c] = __builtin_amdgcn_mfma_f32_16x16x32_bf16(fS, fB, accS[c], 0, 0, 0);
      accF[c] = __builtin_amdgcn_mfma_f32_16x16x32_bf16(fF, fB, accF[c], 0, 0, 0);
      accP[c] = __builtin_amdgcn_mfma_f32_16x16x32_bf16(fP, fB, accP[c], 0, 0, 0);
    }
  }

  const size_t base = (size_t)ks * ((size_t)NN * HH);
#pragma unroll
  for (int c = 0; c < 4; ++c) {
#pragma unroll
    for (int r = 0; r < 4; ++r) {
      const int row = i0 + kgrp * 4 + r;
      const int col = c * 16 + row16;
      const size_t idx = base + (size_t)row * HH + col;
      SpP[idx] = accS[c][r];
      TfP[idx] = accF[c][r];
      TpP[idx] = accP[c][r];
    }
  }
}

// ---------------------------------------------------------------- fused epilogue (cnt from int array)
template <int KSP>
__global__ __launch_bounds__(256) void k_epi(
    const float* __restrict__ h, const float* __restrict__ dn_g,
    const float* __restrict__ de_g, const float* __restrict__ Hb,
    const float* __restrict__ SpP, const float* __restrict__ TfP,
    const float* __restrict__ TpP, const int* __restrict__ cpI,
    const float* __restrict__ wa0, const float* __restrict__ wa1,
    const float* __restrict__ wihTe, const float* __restrict__ whhTe,
    const float* __restrict__ bihe, const float* __restrict__ bhhe,
    const float* __restrict__ WnT, const float* __restrict__ whhTn,
    const float* __restrict__ bihn, const float* __restrict__ bhhn,
    float* __restrict__ out) {
  __shared__ float xs[16][128];
  __shared__ float hs[16][64];
  __shared__ float us[16][64];
  __shared__ float eos[16][64];
  __shared__ float sHb[64], sw0[64], sw1[64];
  const int t = threadIdx.x;
  const int lane = t & 63, w = t >> 6;
  const int i0 = blockIdx.x * 16;
  const size_t SZ = (size_t)NN * HH;

  if (t < 64) {
    sHb[t] = Hb[t];
    sw0[t] = wa0[t];
    sw1[t] = wa1[t];
  }
  {
    const int row = t >> 4, c4 = (t & 15) * 4;
    *reinterpret_cast<float4*>(&hs[row][c4]) =
        *reinterpret_cast<const float4*>(&h[(size_t)(i0 + row) * 64 + c4]);
  }
  __syncthreads();

  for (int rr = 0; rr < 4; ++rr) {
    const int row = w * 4 + rr;
    const size_t idx = (size_t)(i0 + row) * 64 + lane;
    float sp = 0.f, tf = 0.f, tp = 0.f;
#pragma unroll
    for (int s = 0; s < KSP; ++s) {
      sp += SpP[s * SZ + idx];
      tf += TfP[s * SZ + idx];
      tp += TpP[s * SZ + idx];
    }
    const float hv = hs[row][lane];
    const float dni = dn_g[i0 + row], dei = de_g[i0 + row];
    sp -= (dni > 0.f) ? hv : 0.f;
    tf -= dei * hv;
    tp -= fmaxf(dei, 0.f) * hv;
    const float sm = sHb[lane] - hv - sp;
    const float tm = tf - tp;
    float cp = (float)cpI[i0 + row];
    cp -= (dei > 0.f) ? 1.f : 0.f;
    float ep = sp * sw0[lane] + sm * sw1[lane];
    float em = sm * sw0[lane] + sp * sw1[lane];
#pragma unroll
    for (int off = 32; off >= 1; off >>= 1) {
      ep += __shfl_xor(ep, off);
      em += __shfl_xor(em, off);
    }
    ep = ep > 0.f ? ep : LALPHA * ep;
    em = em > 0.f ? em : LALPHA * em;
    const float cm = (float)(NN - 1) - cp;
    const float NEGI = -3.0e38f;
    const float m = fmaxf(cp > 0.f ? ep : NEGI, cm > 0.f ? em : NEGI);
    const float xp = (cp > 0.f) ? expf(ep - m) : 0.f;
    const float xm = (cm > 0.f) ? expf(em - m) : 0.f;
    const float den = cp * xp + cm * xm;
    const float inv = den > 0.f ? 1.f / den : 0.f;
    xs[row][lane] = sp;
    xs[row][64 + lane] = sm;
    us[row][lane] = xp * inv * tp + xm * inv * tm;  // U
  }
  __syncthreads();

  // GRU-edge
  {
    const int c = lane;
    float gi[3][4] = {}, gh[3][4] = {};
    for (int k = 0; k < 128; ++k) {
      const float wr = wihTe[k * 192 + c], wz = wihTe[k * 192 + 64 + c],
                  wn = wihTe[k * 192 + 128 + c];
#pragma unroll
      for (int rr = 0; rr < 4; ++rr) {
        const float x = xs[w * 4 + rr][k];
        gi[0][rr] += x * wr;
        gi[1][rr] += x * wz;
        gi[2][rr] += x * wn;
      }
    }
    for (int k = 0; k < 64; ++k) {
      const float ur = whhTe[k * 192 + c], uz = whhTe[k * 192 + 64 + c],
                  un = whhTe[k * 192 + 128 + c];
#pragma unroll
      for (int rr = 0; rr < 4; ++rr) {
        const float hv = hs[w * 4 + rr][k];
        gh[0][rr] += hv * ur;
        gh[1][rr] += hv * uz;
        gh[2][rr] += hv * un;
      }
    }
    const float br = bihe[c], bz = bihe[64 + c], bn = bihe[128 + c];
    const float dr = bhhe[c], dz = bhhe[64 + c], dnb = bhhe[128 + c];
#pragma unroll
    for (int rr = 0; rr < 4; ++rr) {
      const int row = w * 4 + rr;
      const float rg = 1.f / (1.f + expf(-(gi[0][rr] + br + gh[0][rr] + dr)));
      const float zg = 1.f / (1.f + expf(-(gi[1][rr] + bz + gh[1][rr] + dz)));
      const float ng = tanhf(gi[2][rr] + bn + rg * (gh[2][rr] + dnb));
      eos[row][c] = (1.f - zg) * ng + zg * hs[row][c];
    }
  }
  __syncthreads();

  // GRU-node + final diag combine
  {
    const int c = lane;
    float gi[3][4] = {}, gh[3][4] = {};
    for (int k = 0; k < 64; ++k) {
      const float wr = WnT[k * 192 + c], wz = WnT[k * 192 + 64 + c],
                  wn = WnT[k * 192 + 128 + c];
      const float ur = whhTn[k * 192 + c], uz = whhTn[k * 192 + 64 + c],
                  un = whhTn[k * 192 + 128 + c];
#pragma unroll
      for (int rr = 0; rr < 4; ++rr) {
        const float x = us[w * 4 + rr][k], hv = hs[w * 4 + rr][k];
        gi[0][rr] += x * wr;
        gi[1][rr] += x * wz;
        gi[2][rr] += x * wn;
        gh[0][rr] += hv * ur;
        gh[1][rr] += hv * uz;
        gh[2][rr] += hv * un;
      }
    }
    const float br = bihn[c], bz = bihn[64 + c], bn = bihn[128 + c];
    const float dr = bhhn[c], dz = bhhn[64 + c], dnb = bhhn[128 + c];
#pragma unroll
    for (int rr = 0; rr < 4; ++rr) {
      const int row = w * 4 + rr;
      const float rg = 1.f / (1.f + expf(-(gi[0][rr] + br + gh[0][rr] + dr)));
      const float zg = 1.f / (1.f + expf(-(gi[1][rr] + bz + gh[1][rr] + dz)));
      const float ng = tanhf(gi[2][rr] + bn + rg * (gh[2][rr] + dnb));
      const float no = (1.f - zg) * ng + zg * hs[row][c];
      out[(size_t)(i0 + row) * 64 + c] =
          de_g[i0 + row] * eos[row][c] + dn_g[i0 + row] * no;
    }
  }
}

// ---------------------------------------------------------------- fallback fp32 stageA (r10 body, writes float cnt partials)
template <int KS>
__global__ __launch_bounds__(256, 4) void k_stageAf(
    const float* __restrict__ na, const float* __restrict__ ea,
    const unsigned short* __restrict__ ht,
    float* __restrict__ SpP, float* __restrict__ TfP,
    float* __restrict__ TpP, int* __restrict__ cpI) {
  const int lane  = threadIdx.x & 63;
  const int wid   = threadIdx.x >> 6;
  const int row16 = lane & 15;
  const int kgrp  = lane >> 4;
  const int i0    = blockIdx.x * 64 + wid * 16;
  const int ks    = blockIdx.y;
  const int kbeg  = ks * (NN / KS);
  constexpr int ITERS = NN / KS / 32;
  const int start = blockIdx.x & (ITERS - 1);

  f32x4 accS[4] = {}, accF[4] = {}, accP[4] = {};
  float cnt = 0.f;
  const float* naRow = na + (size_t)(i0 + row16) * NN;
  const float* eaRow = ea + (size_t)(i0 + row16) * NN;

  for (int it = 0; it < ITERS; ++it) {
    int tt = start + it;
    if (tt >= ITERS) tt -= ITERS;
    const int kk = kbeg + tt * 32 + kgrp * 8;
    const float4 a0 = *reinterpret_cast<const float4*>(naRow + kk);
    const float4 a1 = *reinterpret_cast<const float4*>(naRow + kk + 4);
    const float4 e0 = *reinterpret_cast<const float4*>(eaRow + kk);
    const float4 e1 = *reinterpret_cast<const float4*>(eaRow + kk + 4);
    const float av[8] = {a0.x, a0.y, a0.z, a0.w, a1.x, a1.y, a1.z, a1.w};
    const float ev[8] = {e0.x, e0.y, e0.z, e0.w, e1.x, e1.y, e1.z, e1.w};
    bf16x8 fS, fF, fP;
#pragma unroll
    for (int q = 0; q < 8; ++q) {
      fS[q] = (av[q] > 0.f) ? (short)0x3F80 : (short)0;
      fF[q] = f2bf(ev[q]);
      fP[q] = f2bf(fmaxf(ev[q], 0.f));
      cnt += (ev[q] > 0.f) ? 1.f : 0.f;
    }
#pragma unroll
    for (int c = 0; c < 4; ++c) {
      const bf16x8 fB = *reinterpret_cast<const bf16x8*>(
          ht + (size_t)(c * 16 + row16) * NN + kk);
      accS[c] = __builtin_amdgcn_mfma_f32_16x16x32_bf16(fS, fB, accS[c], 0, 0, 0);
      accF[c] = __builtin_amdgcn_mfma_f32_16x16x32_bf16(fF, fB, accF[c], 0, 0, 0);
      accP[c] = __builtin_amdgcn_mfma_f32_16x16x32_bf16(fP, fB, accP[c], 0, 0, 0);
    }
  }
  cnt += __shfl_xor(cnt, 16);
  cnt += __shfl_xor(cnt, 32);
  if (lane < 16) atomicAdd(&cpI[i0 + lane], (int)cnt);

  const size_t base = (size_t)ks * ((size_t)NN * HH);
#pragma unroll
  for (int c = 0; c < 4; ++c) {
#pragma unroll
    for (int r = 0; r < 4; ++r) {
      const int row = i0 + kgrp * 4 + r;
      const int col = c * 16 + row16;
      const size_t idx = base + (size_t)row * HH + col;
      SpP[idx] = accS[c][r];
      TfP[idx] = accF[c][r];
      TpP[idx] = accP[c][r];
    }
  }
}

// ---------------------------------------------------------------- launch
struct WsLayout {
  float *SpP, *TfP, *TpP, *dn, *de, *HbP, *Hb, *wa0, *wa1, *wihTe, *whhTe, *WnT, *whhTn;
  int* cpI;
  unsigned short* ht;
  unsigned char* mask;
  unsigned short* ebf;
};

static WsLayout carve(void* ws, int KS) {
  const size_t SZ = (size_t)NN * HH;
  uintptr_t p = (uintptr_t)ws;
  auto take = [&](size_t bytes) {
    uintptr_t r = (p + 255) & ~(uintptr_t)255;
    p = r + bytes;
    return r;
  };
  WsLayout L;
  L.SpP = (float*)take(KS * SZ * 4);
  L.TfP = (float*)take(KS * SZ * 4);
  L.TpP = (float*)take(KS * SZ * 4);
  L.dn = (float*)take(NN * 4);
  L.de = (float*)take(NN * 4);
  L.HbP = (float*)take(8192 * 4);
  L.Hb = (float*)take(64 * 4);
  L.wa0 = (float*)take(64 * 4);
  L.wa1 = (float*)take(64 * 4);
  L.wihTe = (float*)take(24576 * 4);
  L.whhTe = (float*)take(12288 * 4);
  L.WnT = (float*)take(12288 * 4);
  L.whhTn = (float*)take(12288 * 4);
  L.cpI = (int*)take(NN * 4);
  L.ht = (unsigned short*)take((size_t)NN * 64 * 2);
  L.mask = (unsigned char*)take((size_t)NN * NN / 8);
  L.ebf = (unsigned short*)take((size_t)NN * NN * 2);
  return L;
}

static size_t needBytes(int KS, bool compressed) {
  const size_t SZ = (size_t)NN * HH;
  size_t s = 3 * KS * SZ * 4 + NN * 8 + 8192 * 4 + 64 * 12 + 61440 * 4 + NN * 4 +
             (size_t)NN * 64 * 2 + 17 * 256;
  if (compressed) s += (size_t)NN * NN / 8 + (size_t)NN * NN * 2;
  return s;
}

extern "C" void kernel_launch(void* const* d_in, const int* in_sizes, int n_in,
                              void* d_out, int out_size, void* d_ws, size_t ws_size,
                              hipStream_t stream) {
  const float* h    = (const float*)d_in[0];
  const float* na   = (const float*)d_in[1];
  const float* ea   = (const float*)d_in[2];
  const float* Wg   = (const float*)d_in[3];
  const float* ag   = (const float*)d_in[4];
  const float* wihe = (const float*)d_in[5];
  const float* whhe = (const float*)d_in[6];
  const float* bihe = (const float*)d_in[7];
  const float* bhhe = (const float*)d_in[8];
  const float* wihn = (const float*)d_in[9];
  const float* whhn = (const float*)d_in[10];
  const float* bihn = (const float*)d_in[11];
  const float* bhhn = (const float*)d_in[12];
  float* out = (float*)d_out;

  const bool c8 = ws_size >= needBytes(8, true);
  const bool c4 = !c8 && ws_size >= needBytes(4, true);
  const int KS = (c8 || !c4) ? 8 : 4;
  WsLayout L = carve(d_ws, KS);

  k_prep<<<NN / 64, 256, 0, stream>>>(h, na, ea, L.ht, L.dn, L.de, L.HbP, L.cpI);
  k_wprep<<<65, 256, 0, stream>>>(Wg, ag, wihe, whhe, wihn, whhn, L.HbP, L.Hb,
                                  L.wa0, L.wa1, L.wihTe, L.whhTe, L.WnT, L.whhTn);
  if (c8 || c4) {
    k_prep2<<<2048, 256, 0, stream>>>(na, ea, L.mask, L.ebf, L.cpI);
    if (c8)
      k_stageB<8><<<dim3(NN / 64, 8), 256, 0, stream>>>(L.mask, L.ebf, L.ht,
                                                        L.SpP, L.TfP, L.TpP);
    else
      k_stageB<4><<<dim3(NN / 64, 4), 256, 0, stream>>>(L.mask, L.ebf, L.ht,
                                                        L.SpP, L.TfP, L.TpP);
  } else {
    k_stageAf<8><<<dim3(NN / 64, 8), 256, 0, stream>>>(na, ea, L.ht, L.SpP,
                                                       L.TfP, L.TpP, L.cpI);
  }
  if (c4)
    k_epi<4><<<NN / 16, 256, 0, stream>>>(h, L.dn, L.de, L.Hb, L.SpP, L.TfP,
                                          L.TpP, L.cpI, L.wa0, L.wa1, L.wihTe,
                                          L.whhTe, bihe, bhhe, L.WnT, L.whhTn,
                                          bihn, bhhn, out);
  else
    k_epi<8><<<NN / 16, 256, 0, stream>>>(h, L.dn, L.de, L.Hb, L.SpP, L.TfP,
                                          L.TpP, L.cpI, L.wa0, L.wa1, L.wihTe,
                                          L.whhTe, bihe, bhhe, L.WnT, L.whhTn,
                                          bihn, bhhn, out);
}

// Round 13
// 220.079 us; speedup vs baseline: 1.4245x; 1.4245x over previous
//
#include <hip/hip_runtime.h>

#define NN 8192
#define HH 64
constexpr float LALPHA = 0.2f;

typedef __attribute__((ext_vector_type(8))) short bf16x8;
typedef __attribute__((ext_vector_type(4))) float f32x4;

__device__ inline short f2bf(float f) {
  unsigned u = __builtin_bit_cast(unsigned, f);
  u += 0x7FFFu + ((u >> 16) & 1u);
  return (short)(u >> 16);
}

// ---------------------------------------------------------------- merged prep:
// blocks [0,128): ht transpose band + diag + col-sum partials
// blocks [128,193): weight transposes / folds (wprep)
__global__ __launch_bounds__(256) void k_prepW(
    const float* __restrict__ h, const float* __restrict__ na,
    const float* __restrict__ ea, unsigned short* __restrict__ ht,
    float* __restrict__ dn, float* __restrict__ de, float* __restrict__ HbP,
    const float* __restrict__ W, const float* __restrict__ ag,
    const float* __restrict__ wihe, const float* __restrict__ whhe,
    const float* __restrict__ wihn, const float* __restrict__ whhn,
    float* __restrict__ Hb, float* __restrict__ wa0, float* __restrict__ wa1,
    float* __restrict__ wihTe, float* __restrict__ whhTe,
    float* __restrict__ WnT, float* __restrict__ whhTn) {
  const int t = threadIdx.x;
  if (blockIdx.x < 128) {
    __shared__ float tile[64][65];
    const int j0 = blockIdx.x * 64;
    for (int l = t; l < 64 * 64; l += 256) {
      int r = l >> 6, c = l & 63;
      tile[r][c] = h[(size_t)(j0 + r) * HH + c];
    }
    __syncthreads();
    for (int l = t; l < 64 * 64; l += 256) {
      int c = l >> 6, r = l & 63;
      ht[(size_t)c * NN + j0 + r] = (unsigned short)f2bf(tile[r][c]);
    }
    if (t < 64) {
      float s = 0.f;
      for (int r = 0; r < 64; ++r) s += tile[r][t];
      HbP[blockIdx.x * 64 + t] = s;
    } else if (t < 128) {
      int i = j0 + (t - 64);
      dn[i] = na[(size_t)i * NN + i];
      de[i] = ea[(size_t)i * NN + i];
    }
    return;
  }
  const int bid = blockIdx.x - 128;  // [0,65)
  if (bid == 64) {
    __shared__ float sW[64][64];
    __shared__ float sa[128];
    for (int l = t; l < 4096; l += 256) sW[l >> 6][l & 63] = W[l];
    if (t < 128) sa[t] = ag[t];
    __syncthreads();
    if (t < 64) {
      float s0 = 0.f, s1 = 0.f;
      for (int j = 0; j < 64; ++j) {
        s0 += sW[t][j] * sa[j];
        s1 += sW[t][j] * sa[64 + j];
      }
      wa0[t] = s0;
      wa1[t] = s1;
    }
    return;
  }
  for (int x = bid * 256 + t; x < 49152; x += 64 * 256) {
    if (x < 24576) {
      int k = x / 192, g = x % 192;
      wihTe[x] = wihe[g * 128 + k];
    } else if (x < 36864) {
      int o = x - 24576, k = o / 192, g = o % 192;
      whhTe[o] = whhe[g * 64 + k];
    } else {
      int o = x - 36864, k = o / 192, g = o % 192;
      whhTn[o] = whhn[g * 64 + k];
    }
  }
  if (bid < 48) {
    const int o = bid * 256 + t;
    const int k = o / 192, g = o % 192;
    float s = 0.f;
    for (int j = 0; j < 64; ++j) s += wihn[g * 64 + j] * W[k * 64 + j];
    WnT[o] = s;
  }
}

__global__ __launch_bounds__(64) void k_hbarF(const float* __restrict__ HbP,
                                              float* __restrict__ Hb) {
  int c = threadIdx.x;
  float s = 0.f;
  for (int b = 0; b < 128; ++b) s += HbP[b * 64 + c];
  Hb[c] = s;
}

// ---------------------------------------------------------------- heavy masked matmuls via MFMA
// r10 body (stagger kept) + NONTEMPORAL adjacency loads (ext-vector type for
// the builtin): no L3 allocate -> no install/evict churn on the cyclic stream.
template <int KS>
__global__ __launch_bounds__(256, 4) void k_stageA(
    const float* __restrict__ na, const float* __restrict__ ea,
    const unsigned short* __restrict__ ht,
    float* __restrict__ SpP, float* __restrict__ TfP,
    float* __restrict__ TpP, float* __restrict__ cpP) {
  const int lane  = threadIdx.x & 63;
  const int wid   = threadIdx.x >> 6;
  const int row16 = lane & 15;
  const int kgrp  = lane >> 4;
  const int i0    = blockIdx.x * 64 + wid * 16;
  const int ks    = blockIdx.y;
  const int kbeg  = ks * (NN / KS);
  constexpr int ITERS = NN / KS / 32;
  const int start = blockIdx.x & (ITERS - 1);

  f32x4 accS[4] = {}, accF[4] = {}, accP[4] = {};
  float cnt = 0.f;

  const float* naRow = na + (size_t)(i0 + row16) * NN;
  const float* eaRow = ea + (size_t)(i0 + row16) * NN;

  for (int it = 0; it < ITERS; ++it) {
    int tt = start + it;
    if (tt >= ITERS) tt -= ITERS;
    const int kk = kbeg + tt * 32 + kgrp * 8;
    const f32x4 a0 =
        __builtin_nontemporal_load(reinterpret_cast<const f32x4*>(naRow + kk));
    const f32x4 a1 = __builtin_nontemporal_load(
        reinterpret_cast<const f32x4*>(naRow + kk + 4));
    const f32x4 e0 =
        __builtin_nontemporal_load(reinterpret_cast<const f32x4*>(eaRow + kk));
    const f32x4 e1 = __builtin_nontemporal_load(
        reinterpret_cast<const f32x4*>(eaRow + kk + 4));
    const float av[8] = {a0[0], a0[1], a0[2], a0[3], a1[0], a1[1], a1[2], a1[3]};
    const float ev[8] = {e0[0], e0[1], e0[2], e0[3], e1[0], e1[1], e1[2], e1[3]};
    bf16x8 fS, fF, fP;
#pragma unroll
    for (int q = 0; q < 8; ++q) {
      fS[q] = (av[q] > 0.f) ? (short)0x3F80 : (short)0;
      fF[q] = f2bf(ev[q]);
      fP[q] = f2bf(fmaxf(ev[q], 0.f));
      cnt += (ev[q] > 0.f) ? 1.f : 0.f;
    }
#pragma unroll
    for (int c = 0; c < 4; ++c) {
      const bf16x8 fB = *reinterpret_cast<const bf16x8*>(
          ht + (size_t)(c * 16 + row16) * NN + kk);
      accS[c] = __builtin_amdgcn_mfma_f32_16x16x32_bf16(fS, fB, accS[c], 0, 0, 0);
      accF[c] = __builtin_amdgcn_mfma_f32_16x16x32_bf16(fF, fB, accF[c], 0, 0, 0);
      accP[c] = __builtin_amdgcn_mfma_f32_16x16x32_bf16(fP, fB, accP[c], 0, 0, 0);
    }
  }
  cnt += __shfl_xor(cnt, 16);
  cnt += __shfl_xor(cnt, 32);
  if (lane < 16) cpP[ks * NN + i0 + lane] = cnt;

  const size_t base = (size_t)ks * ((size_t)NN * HH);
#pragma unroll
  for (int c = 0; c < 4; ++c) {
#pragma unroll
    for (int r = 0; r < 4; ++r) {
      const int row = i0 + kgrp * 4 + r;
      const int col = c * 16 + row16;
      const size_t idx = base + (size_t)row * HH + col;
      SpP[idx] = accS[c][r];
      TfP[idx] = accF[c][r];
      TpP[idx] = accP[c][r];
    }
  }
}

// ---------------------------------------------------------------- fused epilogue: cgat + gruE + gruN + final
template <int KSP>
__global__ __launch_bounds__(256) void k_epi(
    const float* __restrict__ h, const float* __restrict__ dn_g,
    const float* __restrict__ de_g, const float* __restrict__ Hb,
    const float* __restrict__ SpP, const float* __restrict__ TfP,
    const float* __restrict__ TpP, const float* __restrict__ cpP,
    const float* __restrict__ wa0, const float* __restrict__ wa1,
    const float* __restrict__ wihTe, const float* __restrict__ whhTe,
    const float* __restrict__ bihe, const float* __restrict__ bhhe,
    const float* __restrict__ WnT, const float* __restrict__ whhTn,
    const float* __restrict__ bihn, const float* __restrict__ bhhn,
    float* __restrict__ out) {
  __shared__ float xs[16][128];
  __shared__ float hs[16][64];
  __shared__ float us[16][64];
  __shared__ float eos[16][64];
  __shared__ float sHb[64], sw0[64], sw1[64];
  const int t = threadIdx.x;
  const int lane = t & 63, w = t >> 6;
  const int i0 = blockIdx.x * 16;
  const size_t SZ = (size_t)NN * HH;

  if (t < 64) {
    sHb[t] = Hb[t];
    sw0[t] = wa0[t];
    sw1[t] = wa1[t];
  }
  {
    const int row = t >> 4, c4 = (t & 15) * 4;
    *reinterpret_cast<float4*>(&hs[row][c4]) =
        *reinterpret_cast<const float4*>(&h[(size_t)(i0 + row) * 64 + c4]);
  }
  __syncthreads();

  for (int rr = 0; rr < 4; ++rr) {
    const int row = w * 4 + rr;
    const size_t idx = (size_t)(i0 + row) * 64 + lane;
    float sp = 0.f, tf = 0.f, tp = 0.f;
#pragma unroll
    for (int s = 0; s < KSP; ++s) {
      sp += SpP[s * SZ + idx];
      tf += TfP[s * SZ + idx];
      tp += TpP[s * SZ + idx];
    }
    const float hv = hs[row][lane];
    const float dni = dn_g[i0 + row], dei = de_g[i0 + row];
    sp -= (dni > 0.f) ? hv : 0.f;
    tf -= dei * hv;
    tp -= fmaxf(dei, 0.f) * hv;
    const float sm = sHb[lane] - hv - sp;
    const float tm = tf - tp;
    float cp = 0.f;
#pragma unroll
    for (int s = 0; s < KSP; ++s) cp += cpP[s * NN + i0 + row];
    cp -= (dei > 0.f) ? 1.f : 0.f;
    float ep = sp * sw0[lane] + sm * sw1[lane];
    float em = sm * sw0[lane] + sp * sw1[lane];
#pragma unroll
    for (int off = 32; off >= 1; off >>= 1) {
      ep += __shfl_xor(ep, off);
      em += __shfl_xor(em, off);
    }
    ep = ep > 0.f ? ep : LALPHA * ep;
    em = em > 0.f ? em : LALPHA * em;
    const float cm = (float)(NN - 1) - cp;
    const float NEGI = -3.0e38f;
    const float m = fmaxf(cp > 0.f ? ep : NEGI, cm > 0.f ? em : NEGI);
    const float xp = (cp > 0.f) ? expf(ep - m) : 0.f;
    const float xm = (cm > 0.f) ? expf(em - m) : 0.f;
    const float den = cp * xp + cm * xm;
    const float inv = den > 0.f ? 1.f / den : 0.f;
    xs[row][lane] = sp;
    xs[row][64 + lane] = sm;
    us[row][lane] = xp * inv * tp + xm * inv * tm;  // U
  }
  __syncthreads();

  // GRU-edge
  {
    const int c = lane;
    float gi[3][4] = {}, gh[3][4] = {};
    for (int k = 0; k < 128; ++k) {
      const float wr = wihTe[k * 192 + c], wz = wihTe[k * 192 + 64 + c],
                  wn = wihTe[k * 192 + 128 + c];
#pragma unroll
      for (int rr = 0; rr < 4; ++rr) {
        const float x = xs[w * 4 + rr][k];
        gi[0][rr] += x * wr;
        gi[1][rr] += x * wz;
        gi[2][rr] += x * wn;
      }
    }
    for (int k = 0; k < 64; ++k) {
      const float ur = whhTe[k * 192 + c], uz = whhTe[k * 192 + 64 + c],
                  un = whhTe[k * 192 + 128 + c];
#pragma unroll
      for (int rr = 0; rr < 4; ++rr) {
        const float hv = hs[w * 4 + rr][k];
        gh[0][rr] += hv * ur;
        gh[1][rr] += hv * uz;
        gh[2][rr] += hv * un;
      }
    }
    const float br = bihe[c], bz = bihe[64 + c], bn = bihe[128 + c];
    const float dr = bhhe[c], dz = bhhe[64 + c], dnb = bhhe[128 + c];
#pragma unroll
    for (int rr = 0; rr < 4; ++rr) {
      const int row = w * 4 + rr;
      const float rg = 1.f / (1.f + expf(-(gi[0][rr] + br + gh[0][rr] + dr)));
      const float zg = 1.f / (1.f + expf(-(gi[1][rr] + bz + gh[1][rr] + dz)));
      const float ng = tanhf(gi[2][rr] + bn + rg * (gh[2][rr] + dnb));
      eos[row][c] = (1.f - zg) * ng + zg * hs[row][c];
    }
  }
  __syncthreads();

  // GRU-node + final diag combine
  {
    const int c = lane;
    float gi[3][4] = {}, gh[3][4] = {};
    for (int k = 0; k < 64; ++k) {
      const float wr = WnT[k * 192 + c], wz = WnT[k * 192 + 64 + c],
                  wn = WnT[k * 192 + 128 + c];
      const float ur = whhTn[k * 192 + c], uz = whhTn[k * 192 + 64 + c],
                  un = whhTn[k * 192 + 128 + c];
#pragma unroll
      for (int rr = 0; rr < 4; ++rr) {
        const float x = us[w * 4 + rr][k], hv = hs[w * 4 + rr][k];
        gi[0][rr] += x * wr;
        gi[1][rr] += x * wz;
        gi[2][rr] += x * wn;
        gh[0][rr] += hv * ur;
        gh[1][rr] += hv * uz;
        gh[2][rr] += hv * un;
      }
    }
    const float br = bihn[c], bz = bihn[64 + c], bn = bihn[128 + c];
    const float dr = bhhn[c], dz = bhhn[64 + c], dnb = bhhn[128 + c];
#pragma unroll
    for (int rr = 0; rr < 4; ++rr) {
      const int row = w * 4 + rr;
      const float rg = 1.f / (1.f + expf(-(gi[0][rr] + br + gh[0][rr] + dr)));
      const float zg = 1.f / (1.f + expf(-(gi[1][rr] + bz + gh[1][rr] + dz)));
      const float ng = tanhf(gi[2][rr] + bn + rg * (gh[2][rr] + dnb));
      const float no = (1.f - zg) * ng + zg * hs[row][c];
      out[(size_t)(i0 + row) * 64 + c] =
          de_g[i0 + row] * eos[row][c] + dn_g[i0 + row] * no;
    }
  }
}

// ---------------------------------------------------------------- launch
template <int KSP>
static void launch_all(const float* h, const float* na, const float* ea,
                       const float* Wg, const float* ag, const float* wihe,
                       const float* whhe, const float* bihe, const float* bhhe,
                       const float* wihn, const float* whhn, const float* bihn,
                       const float* bhhn, float* out, float* ws,
                       hipStream_t stream) {
  const size_t SZ = (size_t)NN * HH;
  float* SpP = ws;
  float* TfP = ws + (size_t)KSP * SZ;
  float* TpP = ws + (size_t)2 * KSP * SZ;
  float* cpP = ws + (size_t)3 * KSP * SZ;
  float* dn = cpP + (size_t)KSP * NN;
  float* de = dn + NN;
  float* HbP = de + NN;          // 128*64
  float* Hb = HbP + 8192;        // 64
  float* wa0 = Hb + 64;
  float* wa1 = wa0 + 64;
  float* wihTe = wa1 + 64;       // 128*192
  float* whhTe = wihTe + 24576;  // 64*192
  float* WnT = whhTe + 12288;    // 64*192
  float* whhTn = WnT + 12288;    // 64*192
  unsigned short* ht = (unsigned short*)(whhTn + 12288);

  k_prepW<<<193, 256, 0, stream>>>(h, na, ea, ht, dn, de, HbP, Wg, ag, wihe,
                                   whhe, wihn, whhn, Hb, wa0, wa1, wihTe,
                                   whhTe, WnT, whhTn);
  k_hbarF<<<1, 64, 0, stream>>>(HbP, Hb);
  k_stageA<KSP><<<dim3(NN / 64, KSP), 256, 0, stream>>>(na, ea, ht, SpP, TfP,
                                                        TpP, cpP);
  k_epi<KSP><<<NN / 16, 256, 0, stream>>>(h, dn, de, Hb, SpP, TfP, TpP, cpP,
                                          wa0, wa1, wihTe, whhTe, bihe, bhhe,
                                          WnT, whhTn, bihn, bhhn, out);
}

extern "C" void kernel_launch(void* const* d_in, const int* in_sizes, int n_in,
                              void* d_out, int out_size, void* d_ws, size_t ws_size,
                              hipStream_t stream) {
  const float* h    = (const float*)d_in[0];
  const float* na   = (const float*)d_in[1];
  const float* ea   = (const float*)d_in[2];
  const float* Wg   = (const float*)d_in[3];
  const float* ag   = (const float*)d_in[4];
  const float* wihe = (const float*)d_in[5];
  const float* whhe = (const float*)d_in[6];
  const float* bihe = (const float*)d_in[7];
  const float* bhhe = (const float*)d_in[8];
  const float* wihn = (const float*)d_in[9];
  const float* whhn = (const float*)d_in[10];
  const float* bihn = (const float*)d_in[11];
  const float* bhhn = (const float*)d_in[12];
  float* out = (float*)d_out;
  float* ws  = (float*)d_ws;

  const size_t SZ = (size_t)NN * HH;
  auto need = [&](int ks) {
    return (3 * (size_t)ks * SZ + (size_t)ks * NN + 2 * NN + 8192 + 192 +
            24576 + 3 * 12288) * 4 + (size_t)NN * HH * 2;
  };
  if (ws_size >= need(8)) {
    launch_all<8>(h, na, ea, Wg, ag, wihe, whhe, bihe, bhhe, wihn, whhn,
                  bihn, bhhn, out, ws, stream);
  } else if (ws_size >= need(4)) {
    launch_all<4>(h, na, ea, Wg, ag, wihe, whhe, bihe, bhhe, wihn, whhn,
                  bihn, bhhn, out, ws, stream);
  } else {
    launch_all<2>(h, na, ea, Wg, ag, wihe, whhe, bihe, bhhe, wihn, whhn,
                  bihn, bhhn, out, ws, stream);
  }
}

// Round 14
// 215.913 us; speedup vs baseline: 1.4520x; 1.0193x over previous
//
#include <hip/hip_runtime.h>

#define NN 8192
#define HH 64
constexpr float LALPHA = 0.2f;

typedef __attribute__((ext_vector_type(8))) short bf16x8;
typedef __attribute__((ext_vector_type(4))) float f32x4;

__device__ inline short f2bf(float f) {
  unsigned u = __builtin_bit_cast(unsigned, f);
  u += 0x7FFFu + ((u >> 16) & 1u);
  return (short)(u >> 16);
}

// ---------------------------------------------------------------- merged prep:
// blocks [0,128): ht transpose band + diag + col-sum partials
// blocks [128,193): weight transposes / folds (wprep)
__global__ __launch_bounds__(256) void k_prepW(
    const float* __restrict__ h, const float* __restrict__ na,
    const float* __restrict__ ea, unsigned short* __restrict__ ht,
    float* __restrict__ dn, float* __restrict__ de, float* __restrict__ HbP,
    const float* __restrict__ W, const float* __restrict__ ag,
    const float* __restrict__ wihe, const float* __restrict__ whhe,
    const float* __restrict__ wihn, const float* __restrict__ whhn,
    float* __restrict__ wa0, float* __restrict__ wa1,
    float* __restrict__ wihTe, float* __restrict__ whhTe,
    float* __restrict__ WnT, float* __restrict__ whhTn) {
  const int t = threadIdx.x;
  if (blockIdx.x < 128) {
    __shared__ float tile[64][65];
    const int j0 = blockIdx.x * 64;
    for (int l = t; l < 64 * 64; l += 256) {
      int r = l >> 6, c = l & 63;
      tile[r][c] = h[(size_t)(j0 + r) * HH + c];
    }
    __syncthreads();
    for (int l = t; l < 64 * 64; l += 256) {
      int c = l >> 6, r = l & 63;
      ht[(size_t)c * NN + j0 + r] = (unsigned short)f2bf(tile[r][c]);
    }
    if (t < 64) {
      float s = 0.f;
      for (int r = 0; r < 64; ++r) s += tile[r][t];
      HbP[blockIdx.x * 64 + t] = s;
    } else if (t < 128) {
      int i = j0 + (t - 64);
      dn[i] = na[(size_t)i * NN + i];
      de[i] = ea[(size_t)i * NN + i];
    }
    return;
  }
  const int bid = blockIdx.x - 128;  // [0,65)
  if (bid == 64) {
    __shared__ float sW[64][64];
    __shared__ float sa[128];
    for (int l = t; l < 4096; l += 256) sW[l >> 6][l & 63] = W[l];
    if (t < 128) sa[t] = ag[t];
    __syncthreads();
    if (t < 64) {
      float s0 = 0.f, s1 = 0.f;
      for (int j = 0; j < 64; ++j) {
        s0 += sW[t][j] * sa[j];
        s1 += sW[t][j] * sa[64 + j];
      }
      wa0[t] = s0;
      wa1[t] = s1;
    }
    return;
  }
  for (int x = bid * 256 + t; x < 49152; x += 64 * 256) {
    if (x < 24576) {
      int k = x / 192, g = x % 192;
      wihTe[x] = wihe[g * 128 + k];
    } else if (x < 36864) {
      int o = x - 24576, k = o / 192, g = o % 192;
      whhTe[o] = whhe[g * 64 + k];
    } else {
      int o = x - 36864, k = o / 192, g = o % 192;
      whhTn[o] = whhn[g * 64 + k];
    }
  }
  if (bid < 48) {
    const int o = bid * 256 + t;
    const int k = o / 192, g = o % 192;
    float s = 0.f;
    for (int j = 0; j < 64; ++j) s += wihn[g * 64 + j] * W[k * 64 + j];
    WnT[o] = s;
  }
}

// ---------------------------------------------------------------- heavy masked matmuls via MFMA
// r13 body (stagger + nt adjacency loads) + nt partial stores + folded Hb
// reduction (block (0,0) reduces HbP at start, overlapped with other blocks).
template <int KS>
__global__ __launch_bounds__(256, 4) void k_stageA(
    const float* __restrict__ na, const float* __restrict__ ea,
    const unsigned short* __restrict__ ht,
    float* __restrict__ SpP, float* __restrict__ TfP,
    float* __restrict__ TpP, float* __restrict__ cpP,
    const float* __restrict__ HbP, float* __restrict__ Hb) {
  const int lane  = threadIdx.x & 63;
  const int wid   = threadIdx.x >> 6;
  const int row16 = lane & 15;
  const int kgrp  = lane >> 4;
  const int i0    = blockIdx.x * 64 + wid * 16;
  const int ks    = blockIdx.y;
  const int kbeg  = ks * (NN / KS);
  constexpr int ITERS = NN / KS / 32;
  const int start = blockIdx.x & (ITERS - 1);

  // folded column-sum finalization (one block; overlaps with grid's main work)
  if (blockIdx.x == 0 && ks == 0 && threadIdx.x < 64) {
    float s = 0.f;
    for (int b = 0; b < 128; ++b) s += HbP[b * 64 + threadIdx.x];
    Hb[threadIdx.x] = s;
  }

  f32x4 accS[4] = {}, accF[4] = {}, accP[4] = {};
  float cnt = 0.f;

  const float* naRow = na + (size_t)(i0 + row16) * NN;
  const float* eaRow = ea + (size_t)(i0 + row16) * NN;

  for (int it = 0; it < ITERS; ++it) {
    int tt = start + it;
    if (tt >= ITERS) tt -= ITERS;
    const int kk = kbeg + tt * 32 + kgrp * 8;
    const f32x4 a0 =
        __builtin_nontemporal_load(reinterpret_cast<const f32x4*>(naRow + kk));
    const f32x4 a1 = __builtin_nontemporal_load(
        reinterpret_cast<const f32x4*>(naRow + kk + 4));
    const f32x4 e0 =
        __builtin_nontemporal_load(reinterpret_cast<const f32x4*>(eaRow + kk));
    const f32x4 e1 = __builtin_nontemporal_load(
        reinterpret_cast<const f32x4*>(eaRow + kk + 4));
    const float av[8] = {a0[0], a0[1], a0[2], a0[3], a1[0], a1[1], a1[2], a1[3]};
    const float ev[8] = {e0[0], e0[1], e0[2], e0[3], e1[0], e1[1], e1[2], e1[3]};
    bf16x8 fS, fF, fP;
#pragma unroll
    for (int q = 0; q < 8; ++q) {
      fS[q] = (av[q] > 0.f) ? (short)0x3F80 : (short)0;
      fF[q] = f2bf(ev[q]);
      fP[q] = f2bf(fmaxf(ev[q], 0.f));
      cnt += (ev[q] > 0.f) ? 1.f : 0.f;
    }
#pragma unroll
    for (int c = 0; c < 4; ++c) {
      const bf16x8 fB = *reinterpret_cast<const bf16x8*>(
          ht + (size_t)(c * 16 + row16) * NN + kk);
      accS[c] = __builtin_amdgcn_mfma_f32_16x16x32_bf16(fS, fB, accS[c], 0, 0, 0);
      accF[c] = __builtin_amdgcn_mfma_f32_16x16x32_bf16(fF, fB, accF[c], 0, 0, 0);
      accP[c] = __builtin_amdgcn_mfma_f32_16x16x32_bf16(fP, fB, accP[c], 0, 0, 0);
    }
  }
  cnt += __shfl_xor(cnt, 16);
  cnt += __shfl_xor(cnt, 32);
  if (lane < 16) cpP[ks * NN + i0 + lane] = cnt;

  const size_t base = (size_t)ks * ((size_t)NN * HH);
#pragma unroll
  for (int c = 0; c < 4; ++c) {
#pragma unroll
    for (int r = 0; r < 4; ++r) {
      const int row = i0 + kgrp * 4 + r;
      const int col = c * 16 + row16;
      const size_t idx = base + (size_t)row * HH + col;
      __builtin_nontemporal_store(accS[c][r], &SpP[idx]);
      __builtin_nontemporal_store(accF[c][r], &TfP[idx]);
      __builtin_nontemporal_store(accP[c][r], &TpP[idx]);
    }
  }
}

// ---------------------------------------------------------------- fused epilogue: cgat + gruE + gruN + final
template <int KSP>
__global__ __launch_bounds__(256) void k_epi(
    const float* __restrict__ h, const float* __restrict__ dn_g,
    const float* __restrict__ de_g, const float* __restrict__ Hb,
    const float* __restrict__ SpP, const float* __restrict__ TfP,
    const float* __restrict__ TpP, const float* __restrict__ cpP,
    const float* __restrict__ wa0, const float* __restrict__ wa1,
    const float* __restrict__ wihTe, const float* __restrict__ whhTe,
    const float* __restrict__ bihe, const float* __restrict__ bhhe,
    const float* __restrict__ WnT, const float* __restrict__ whhTn,
    const float* __restrict__ bihn, const float* __restrict__ bhhn,
    float* __restrict__ out) {
  __shared__ float xs[16][128];
  __shared__ float hs[16][64];
  __shared__ float us[16][64];
  __shared__ float eos[16][64];
  __shared__ float sHb[64], sw0[64], sw1[64];
  const int t = threadIdx.x;
  const int lane = t & 63, w = t >> 6;
  const int i0 = blockIdx.x * 16;
  const size_t SZ = (size_t)NN * HH;

  if (t < 64) {
    sHb[t] = Hb[t];
    sw0[t] = wa0[t];
    sw1[t] = wa1[t];
  }
  {
    const int row = t >> 4, c4 = (t & 15) * 4;
    *reinterpret_cast<float4*>(&hs[row][c4]) =
        *reinterpret_cast<const float4*>(&h[(size_t)(i0 + row) * 64 + c4]);
  }
  __syncthreads();

  for (int rr = 0; rr < 4; ++rr) {
    const int row = w * 4 + rr;
    const size_t idx = (size_t)(i0 + row) * 64 + lane;
    float sp = 0.f, tf = 0.f, tp = 0.f;
#pragma unroll
    for (int s = 0; s < KSP; ++s) {
      sp += __builtin_nontemporal_load(&SpP[s * SZ + idx]);
      tf += __builtin_nontemporal_load(&TfP[s * SZ + idx]);
      tp += __builtin_nontemporal_load(&TpP[s * SZ + idx]);
    }
    const float hv = hs[row][lane];
    const float dni = dn_g[i0 + row], dei = de_g[i0 + row];
    sp -= (dni > 0.f) ? hv : 0.f;
    tf -= dei * hv;
    tp -= fmaxf(dei, 0.f) * hv;
    const float sm = sHb[lane] - hv - sp;
    const float tm = tf - tp;
    float cp = 0.f;
#pragma unroll
    for (int s = 0; s < KSP; ++s) cp += cpP[s * NN + i0 + row];
    cp -= (dei > 0.f) ? 1.f : 0.f;
    float ep = sp * sw0[lane] + sm * sw1[lane];
    float em = sm * sw0[lane] + sp * sw1[lane];
#pragma unroll
    for (int off = 32; off >= 1; off >>= 1) {
      ep += __shfl_xor(ep, off);
      em += __shfl_xor(em, off);
    }
    ep = ep > 0.f ? ep : LALPHA * ep;
    em = em > 0.f ? em : LALPHA * em;
    const float cm = (float)(NN - 1) - cp;
    const float NEGI = -3.0e38f;
    const float m = fmaxf(cp > 0.f ? ep : NEGI, cm > 0.f ? em : NEGI);
    const float xp = (cp > 0.f) ? expf(ep - m) : 0.f;
    const float xm = (cm > 0.f) ? expf(em - m) : 0.f;
    const float den = cp * xp + cm * xm;
    const float inv = den > 0.f ? 1.f / den : 0.f;
    xs[row][lane] = sp;
    xs[row][64 + lane] = sm;
    us[row][lane] = xp * inv * tp + xm * inv * tm;  // U
  }
  __syncthreads();

  // GRU-edge
  {
    const int c = lane;
    float gi[3][4] = {}, gh[3][4] = {};
    for (int k = 0; k < 128; ++k) {
      const float wr = wihTe[k * 192 + c], wz = wihTe[k * 192 + 64 + c],
                  wn = wihTe[k * 192 + 128 + c];
#pragma unroll
      for (int rr = 0; rr < 4; ++rr) {
        const float x = xs[w * 4 + rr][k];
        gi[0][rr] += x * wr;
        gi[1][rr] += x * wz;
        gi[2][rr] += x * wn;
      }
    }
    for (int k = 0; k < 64; ++k) {
      const float ur = whhTe[k * 192 + c], uz = whhTe[k * 192 + 64 + c],
                  un = whhTe[k * 192 + 128 + c];
#pragma unroll
      for (int rr = 0; rr < 4; ++rr) {
        const float hv = hs[w * 4 + rr][k];
        gh[0][rr] += hv * ur;
        gh[1][rr] += hv * uz;
        gh[2][rr] += hv * un;
      }
    }
    const float br = bihe[c], bz = bihe[64 + c], bn = bihe[128 + c];
    const float dr = bhhe[c], dz = bhhe[64 + c], dnb = bhhe[128 + c];
#pragma unroll
    for (int rr = 0; rr < 4; ++rr) {
      const int row = w * 4 + rr;
      const float rg = 1.f / (1.f + expf(-(gi[0][rr] + br + gh[0][rr] + dr)));
      const float zg = 1.f / (1.f + expf(-(gi[1][rr] + bz + gh[1][rr] + dz)));
      const float ng = tanhf(gi[2][rr] + bn + rg * (gh[2][rr] + dnb));
      eos[row][c] = (1.f - zg) * ng + zg * hs[row][c];
    }
  }
  __syncthreads();

  // GRU-node + final diag combine
  {
    const int c = lane;
    float gi[3][4] = {}, gh[3][4] = {};
    for (int k = 0; k < 64; ++k) {
      const float wr = WnT[k * 192 + c], wz = WnT[k * 192 + 64 + c],
                  wn = WnT[k * 192 + 128 + c];
      const float ur = whhTn[k * 192 + c], uz = whhTn[k * 192 + 64 + c],
                  un = whhTn[k * 192 + 128 + c];
#pragma unroll
      for (int rr = 0; rr < 4; ++rr) {
        const float x = us[w * 4 + rr][k], hv = hs[w * 4 + rr][k];
        gi[0][rr] += x * wr;
        gi[1][rr] += x * wz;
        gi[2][rr] += x * wn;
        gh[0][rr] += hv * ur;
        gh[1][rr] += hv * uz;
        gh[2][rr] += hv * un;
      }
    }
    const float br = bihn[c], bz = bihn[64 + c], bn = bihn[128 + c];
    const float dr = bhhn[c], dz = bhhn[64 + c], dnb = bhhn[128 + c];
#pragma unroll
    for (int rr = 0; rr < 4; ++rr) {
      const int row = w * 4 + rr;
      const float rg = 1.f / (1.f + expf(-(gi[0][rr] + br + gh[0][rr] + dr)));
      const float zg = 1.f / (1.f + expf(-(gi[1][rr] + bz + gh[1][rr] + dz)));
      const float ng = tanhf(gi[2][rr] + bn + rg * (gh[2][rr] + dnb));
      const float no = (1.f - zg) * ng + zg * hs[row][c];
      out[(size_t)(i0 + row) * 64 + c] =
          de_g[i0 + row] * eos[row][c] + dn_g[i0 + row] * no;
    }
  }
}

// ---------------------------------------------------------------- launch
template <int KSP>
static void launch_all(const float* h, const float* na, const float* ea,
                       const float* Wg, const float* ag, const float* wihe,
                       const float* whhe, const float* bihe, const float* bhhe,
                       const float* wihn, const float* whhn, const float* bihn,
                       const float* bhhn, float* out, float* ws,
                       hipStream_t stream) {
  const size_t SZ = (size_t)NN * HH;
  float* SpP = ws;
  float* TfP = ws + (size_t)KSP * SZ;
  float* TpP = ws + (size_t)2 * KSP * SZ;
  float* cpP = ws + (size_t)3 * KSP * SZ;
  float* dn = cpP + (size_t)KSP * NN;
  float* de = dn + NN;
  float* HbP = de + NN;          // 128*64
  float* Hb = HbP + 8192;        // 64
  float* wa0 = Hb + 64;
  float* wa1 = wa0 + 64;
  float* wihTe = wa1 + 64;       // 128*192
  float* whhTe = wihTe + 24576;  // 64*192
  float* WnT = whhTe + 12288;    // 64*192
  float* whhTn = WnT + 12288;    // 64*192
  unsigned short* ht = (unsigned short*)(whhTn + 12288);

  k_prepW<<<193, 256, 0, stream>>>(h, na, ea, ht, dn, de, HbP, Wg, ag, wihe,
                                   whhe, wihn, whhn, wa0, wa1, wihTe, whhTe,
                                   WnT, whhTn);
  k_stageA<KSP><<<dim3(NN / 64, KSP), 256, 0, stream>>>(na, ea, ht, SpP, TfP,
                                                        TpP, cpP, HbP, Hb);
  k_epi<KSP><<<NN / 16, 256, 0, stream>>>(h, dn, de, Hb, SpP, TfP, TpP, cpP,
                                          wa0, wa1, wihTe, whhTe, bihe, bhhe,
                                          WnT, whhTn, bihn, bhhn, out);
}

extern "C" void kernel_launch(void* const* d_in, const int* in_sizes, int n_in,
                              void* d_out, int out_size, void* d_ws, size_t ws_size,
                              hipStream_t stream) {
  const float* h    = (const float*)d_in[0];
  const float* na   = (const float*)d_in[1];
  const float* ea   = (const float*)d_in[2];
  const float* Wg   = (const float*)d_in[3];
  const float* ag   = (const float*)d_in[4];
  const float* wihe = (const float*)d_in[5];
  const float* whhe = (const float*)d_in[6];
  const float* bihe = (const float*)d_in[7];
  const float* bhhe = (const float*)d_in[8];
  const float* wihn = (const float*)d_in[9];
  const float* whhn = (const float*)d_in[10];
  const float* bihn = (const float*)d_in[11];
  const float* bhhn = (const float*)d_in[12];
  float* out = (float*)d_out;
  float* ws  = (float*)d_ws;

  const size_t SZ = (size_t)NN * HH;
  auto need = [&](int ks) {
    return (3 * (size_t)ks * SZ + (size_t)ks * NN + 2 * NN + 8192 + 192 +
            24576 + 3 * 12288) * 4 + (size_t)NN * HH * 2;
  };
  if (ws_size >= need(8)) {
    launch_all<8>(h, na, ea, Wg, ag, wihe, whhe, bihe, bhhe, wihn, whhn,
                  bihn, bhhn, out, ws, stream);
  } else if (ws_size >= need(4)) {
    launch_all<4>(h, na, ea, Wg, ag, wihe, whhe, bihe, bhhe, wihn, whhn,
                  bihn, bhhn, out, ws, stream);
  } else {
    launch_all<2>(h, na, ea, Wg, ag, wihe, whhe, bihe, bhhe, wihn, whhn,
                  bihn, bhhn, out, ws, stream);
  }
}